// Round 2
// 166.679 us; speedup vs baseline: 1.0248x; 1.0248x over previous
//
#include <hip/hip_runtime.h>

// Problem: B=64, K=17, H=128, W=128, RATIO=0.25, SIGMA=2.0
constexpr int   HW     = 16384;
constexpr int   NSLICE = 1088;          // 64*17
constexpr int   GTMAX  = 4096;          // pxl_num; kthvalue rank 12288 from bottom
constexpr float LO0    = 0.72f;         // static bracket around 0.75-quantile of U(0,1)
constexpr float HI0    = 0.78f;         // ~±9 sigma of the sample quantile -> fallback ~never
constexpr int   CAP    = 1280;          // per-slice window capacity (mean ~983, sigma ~30)
constexpr int   BINS   = 1024;          // counting-refinement buckets
constexpr float BSCALE = (float)BINS / (HI0 - LO0);

constexpr int NT1 = 512;                // K1 threads (8 waves)
constexpr int V41 = 8;                  // float4 per thread in K1
constexpr int NT3 = 256;                // K2 threads (4 waves)
constexpr int QPS = 4;                  // K2 blocks per slice
constexpr int V43 = 4;                  // float4 per thread per array in K2
constexpr int NPART = NSLICE * QPS;     // 4352

__device__ __forceinline__ int bucket_of(float x) {
    int b = (int)((x - LO0) * BSCALE);  // monotone on (LO0, HI0]
    return b < 0 ? 0 : (b > BINS - 1 ? BINS - 1 : b);
}

// ---------------- K1: stream tgt once, select exact threshold, store th+argmax ----------------
__global__ __launch_bounds__(NT1) void k1_scan_select(
    const float* __restrict__ tgt,
    float* __restrict__ th_out, int* __restrict__ mi_out)
{
    __shared__ float s_w[CAP];           // 5 KB compacted window
    __shared__ int   hist[BINS];         // 4 KB
    __shared__ float redf[8];
    __shared__ int   redi[8], redh[8], wtot[8], wcnt[8];
    __shared__ float cands[64];
    __shared__ int   s_n, s_nc, s_bstar, s_above;
    __shared__ float s_th;

    const int t = threadIdx.x, lane = t & 63, wid = t >> 6;
    const int bid = blockIdx.x;
    const float4* t4 = reinterpret_cast<const float4*>(tgt) + (size_t)bid * (HW / 4);

    for (int i = t; i < BINS; i += NT1) hist[i] = 0;
    if (t == 0) { s_n = 0; s_nc = 0; }
    __syncthreads();

    // stream tgt (8 loads issued up-front)
    float4 va[V41];
    #pragma unroll
    for (int j = 0; j < V41; ++j) va[j] = t4[j * NT1 + t];

    float bmax = -1.f; int bmi = 0; int hic = 0;
    #pragma unroll
    for (int j = 0; j < V41; ++j) {
        const int base = (j * NT1 + t) * 4;
        float a[4] = {va[j].x, va[j].y, va[j].z, va[j].w};
        #pragma unroll
        for (int c = 0; c < 4; ++c) {
            float x = a[c];
            if (x > bmax) { bmax = x; bmi = base + c; }   // per-thread idx increasing
            hic += (x > HI0) ? 1 : 0;
            if (x > LO0 && x <= HI0) {
                int p = atomicAdd(&s_n, 1);
                if (p < CAP) s_w[p] = x;
            }
        }
    }
    // block reduce: argmax (first-max tie rule) + #(>HI0)
    #pragma unroll
    for (int off = 32; off > 0; off >>= 1) {
        float ov = __shfl_down(bmax, off);
        int   oi = __shfl_down(bmi, off);
        int   oh = __shfl_down(hic, off);
        if (ov > bmax || (ov == bmax && oi < bmi)) { bmax = ov; bmi = oi; }
        hic += oh;
    }
    if (lane == 0) { redf[wid] = bmax; redi[wid] = bmi; redh[wid] = hic; }
    __syncthreads();   // orders s_w/s_n/red* before reads

    float mv = redf[0]; int mi = redi[0]; int hi0 = 0;
    #pragma unroll
    for (int w = 0; w < 8; ++w) {
        if (redf[w] > mv || (redf[w] == mv && redi[w] < mi)) { mv = redf[w]; mi = redi[w]; }
        hi0 += redh[w];
    }
    const int n_raw = s_n;
    const int n     = n_raw < CAP ? n_raw : CAP;
    const int need  = (GTMAX + 1) - hi0;            // rank-from-top within window
    const bool valid = (n_raw <= CAP) && (hi0 <= GTMAX) && (need <= n_raw);

    float th = 0.f;
    bool done = false;                   // block-uniform throughout
    if (valid) {
        // histogram the compacted window
        for (int i = t; i < n; i += NT1) atomicAdd(&hist[bucket_of(s_w[i])], 1);
        __syncthreads();
        // suffix scan from top bucket: thread t owns bins 2t, 2t+1
        const int h0 = hist[2 * t], h1 = hist[2 * t + 1];
        const int lsum = h0 + h1;
        int incl = lsum;
        #pragma unroll
        for (int off = 1; off < 64; off <<= 1) {
            int v = __shfl_down(incl, off);
            incl += (lane + off < 64) ? v : 0;
        }
        if (lane == 0) wtot[wid] = incl;
        __syncthreads();
        int suf = incl - lsum;
        #pragma unroll
        for (int w = 0; w < 8; ++w) suf += (w > wid) ? wtot[w] : 0;
        int running = suf;               // above bucket 2t+1
        if (running < need && need <= running + h1) { s_bstar = 2 * t + 1; s_above = running; }
        running += h1;                   // above bucket 2t
        if (running < need && need <= running + h0) { s_bstar = 2 * t;     s_above = running; }
        __syncthreads();
        const int bstar = s_bstar, above = s_above;
        const int cnum  = hist[bstar];   // block-uniform
        if (cnum <= 64) {
            for (int i = t; i < n; i += NT1) {
                float x = s_w[i];
                if (bucket_of(x) == bstar) { int pos = atomicAdd(&s_nc, 1); cands[pos] = x; }
            }
            __syncthreads();
            const int m = s_nc;          // == cnum, usually 1-2
            for (int i = t; i < m; i += NT1) {
                float ci = cands[i];
                int gt = 0, eq = 0;
                for (int j = 0; j < m; ++j) {
                    float cj = cands[j];
                    gt += (cj > ci) ? 1 : 0; eq += (cj == ci) ? 1 : 0;
                }
                int gg = hi0 + above + gt;
                if (gg <= GTMAX && gg + eq >= GTMAX + 1) s_th = ci;
            }
            __syncthreads();
            th = s_th;
            done = true;
        }
    }
    if (!done) {
        // exact fallback (~never): value bisection re-reading this slice (L2/L3-warm)
        float lo = -1.0f, hiv = mv;
        int g_lo = HW, g_hiC = 0;
        bool degen = false;
        while (g_lo - g_hiC > 48) {
            float mid = 0.5f * (lo + hiv);
            if (!(mid > lo && mid < hiv)) { degen = true; break; }
            int cnt = 0;
            for (int j = 0; j < V41; ++j) {
                float4 v = t4[j * NT1 + t];
                cnt += (v.x > mid) + (v.y > mid) + (v.z > mid) + (v.w > mid);
            }
            #pragma unroll
            for (int off = 32; off > 0; off >>= 1) cnt += __shfl_down(cnt, off);
            if (lane == 0) wcnt[wid] = cnt;
            __syncthreads();
            int g = 0;
            #pragma unroll
            for (int w = 0; w < 8; ++w) g += wcnt[w];
            __syncthreads();
            if (g >= GTMAX + 1) { lo = mid; g_lo = g; }
            else                { hiv = mid; g_hiC = g; }
        }
        if (degen) th = hiv;
        else {
            if (t == 0) s_nc = 0;
            __syncthreads();
            for (int j = 0; j < V41; ++j) {
                float4 v = t4[j * NT1 + t];
                float a[4] = {v.x, v.y, v.z, v.w};
                for (int c = 0; c < 4; ++c) {
                    float x = a[c];
                    if (x > lo && x <= hiv) { int pos = atomicAdd(&s_nc, 1); if (pos < 64) cands[pos] = x; }
                }
            }
            __syncthreads();
            int m = s_nc; m = m > 64 ? 64 : m;
            for (int i = t; i < m; i += NT1) {
                float ci = cands[i];
                int gt = 0, eq = 0;
                for (int j = 0; j < m; ++j) {
                    float cj = cands[j];
                    gt += (cj > ci) ? 1 : 0; eq += (cj == ci) ? 1 : 0;
                }
                int gg = g_hiC + gt;
                if (gg <= GTMAX && gg + eq >= GTMAX + 1) s_th = ci;
            }
            __syncthreads();
            th = s_th;
        }
    }
    if (t == 0) { th_out[bid] = th; mi_out[bid] = mi; }
}

// ---------------- K2: pure streaming masked MSE (quarter-slice per block) ----------------
// g = exp(-d2/8) only within the 31x31 box (outside g<=1.3e-14; error ~1e-11).
__global__ __launch_bounds__(NT3, 8) void k2_mse(
    const float* __restrict__ pred, const float* __restrict__ tgt,
    const float* __restrict__ th_in, const int* __restrict__ mi_in,
    float* __restrict__ part)
{
    __shared__ float redf[4];
    const int t = threadIdx.x, lane = t & 63, wid = t >> 6;
    const int bid = blockIdx.x;
    const int s = bid >> 2, q = bid & 3;
    const float th = th_in[s];
    const int mi = mi_in[s];
    const int cyi = mi >> 7, cxi = mi & 127;
    const float4* t4 = reinterpret_cast<const float4*>(tgt)  + (size_t)s * (HW / 4) + q * 1024;
    const float4* p4 = reinterpret_cast<const float4*>(pred) + (size_t)s * (HW / 4) + q * 1024;

    float4 tv[V43], pv[V43];
    #pragma unroll
    for (int j = 0; j < V43; ++j) { tv[j] = t4[j * NT3 + t]; pv[j] = p4[j * NT3 + t]; }

    float sum = 0.f;
    #pragma unroll
    for (int j = 0; j < V43; ++j) {
        const int base = (q * 1024 + j * NT3 + t) * 4;
        float at[4] = {tv[j].x, tv[j].y, tv[j].z, tv[j].w};
        float ap[4] = {pv[j].x, pv[j].y, pv[j].z, pv[j].w};
        #pragma unroll
        for (int c = 0; c < 4; ++c) {
            if (at[c] > th) {
                const int idx = base + c;
                const int dy = (idx >> 7) - cyi, dx = (idx & 127) - cxi;
                float p = ap[c];
                if (dy >= -15 && dy <= 15 && dx >= -15 && dx <= 15) {
                    float g = __expf((float)(dy * dy + dx * dx) * -0.125f);
                    float d = p - g;
                    sum += d * d;
                } else {
                    sum += p * p;
                }
            }
        }
    }
    #pragma unroll
    for (int off = 32; off > 0; off >>= 1) sum += __shfl_down(sum, off);
    if (lane == 0) redf[wid] = sum;
    __syncthreads();
    if (t == 0) part[bid] = (redf[0] + redf[1]) + (redf[2] + redf[3]);
}

// ---------------- K3: final reduce ----------------
__global__ __launch_bounds__(256) void k3_final(
    const float* __restrict__ part, float* __restrict__ out)
{
    __shared__ float red[4];
    const int t = threadIdx.x;
    float s = 0.f;
    for (int i = t; i < NPART; i += 256) s += part[i];
    #pragma unroll
    for (int off = 32; off > 0; off >>= 1) s += __shfl_down(s, off);
    if ((t & 63) == 0) red[t >> 6] = s;
    __syncthreads();
    if (t == 0)
        out[0] = ((red[0] + red[1]) + (red[2] + red[3]))
                 * (1.0f / ((float)GTMAX * (float)NSLICE));   // / pxl_num / (B*K)
}

extern "C" void kernel_launch(void* const* d_in, const int* in_sizes, int n_in,
                              void* d_out, int out_size, void* d_ws, size_t ws_size,
                              hipStream_t stream)
{
    const float* pred = (const float*)d_in[0];   // "output" in reference
    const float* tgt  = (const float*)d_in[1];   // "target"
    float* out = (float*)d_out;

    // workspace layout (floats): [0,1088) th | [1088,2176) mi (int) | [2176,6528) partials
    float* th   = (float*)d_ws;
    int*   mi   = (int*)(th + NSLICE);
    float* part = (float*)(mi + NSLICE);

    k1_scan_select<<<NSLICE,       NT1, 0, stream>>>(tgt, th, mi);
    k2_mse        <<<NSLICE * QPS, NT3, 0, stream>>>(pred, tgt, th, mi, part);
    k3_final      <<<1,            256, 0, stream>>>(part, out);
}

// Round 3
// 165.752 us; speedup vs baseline: 1.0305x; 1.0056x over previous
//
#include <hip/hip_runtime.h>

// Problem: B=64, K=17, H=128, W=128, RATIO=0.25, SIGMA=2.0
constexpr int   HW     = 16384;
constexpr int   NSLICE = 1088;          // 64*17
constexpr int   GTMAX  = 4096;          // pxl_num; kthvalue rank 12288 from bottom
constexpr float LO0    = 0.735f;        // static bracket around 0.75-quantile of U(0,1)
constexpr float HI0    = 0.770f;        // runtime-validated; exact fallback otherwise
constexpr int   SLOTS  = 10;            // per-thread stash (mean 1.12, P(ovf/launch)~2e-2)
constexpr int   SSTR   = 11;            // stash stride pad (breaks LDS bank conflicts)
constexpr int   BINS   = 1024;          // counting-refinement buckets
constexpr float BSCALE = (float)BINS / (HI0 - LO0);

constexpr int NT1 = 512;                // K1 threads (8 waves)
constexpr int V41 = 8;                  // float4 per thread in K1
constexpr int NT3 = 256;                // K2 threads (4 waves)
constexpr int QPS = 4;                  // K2 blocks per slice
constexpr int V43 = 4;                  // float4 per thread per array in K2
constexpr int NPART = NSLICE * QPS;     // 4352

__device__ __forceinline__ int bucket_of(float x) {
    int b = (int)((x - LO0) * BSCALE);  // monotone on (LO0, HI0]
    return b < 0 ? 0 : (b > BINS - 1 ? BINS - 1 : b);
}

// ---------------- K1: stream tgt once (per-thread stash), exact threshold, store th+argmax ----
__global__ __launch_bounds__(NT1, 6) void k1_scan_select(
    const float* __restrict__ tgt,
    float* __restrict__ th_out, int* __restrict__ mi_out)
{
    __shared__ int   hist[BINS];          // 4 KB
    __shared__ float sval[NT1 * SSTR];    // 22.5 KB per-thread stash
    __shared__ float redf[8];
    __shared__ int   redi[8];
    __shared__ int   whi[8], wwin[8], wovf[8], wcnt[8], wtot[8];
    __shared__ float cands[64];
    __shared__ int   s_nc, s_bstar, s_above;
    __shared__ float s_th;

    const int t = threadIdx.x, lane = t & 63, wid = t >> 6;
    const int bid = blockIdx.x;
    const float4* t4 = reinterpret_cast<const float4*>(tgt) + (size_t)bid * (HW / 4);
    const int sbase = t * SSTR;

    #pragma unroll
    for (int i = t; i < BINS; i += NT1) hist[i] = 0;
    if (t == 0) s_nc = 0;

    // ---- Pass 1: stream tgt once. 8 loads issued up-front (MLP), then process ----
    float4 va[V41];
    #pragma unroll
    for (int j = 0; j < V41; ++j) va[j] = t4[j * NT1 + t];

    float bmax = -1.f; int bmi = 0;
    int hic = 0, myn = 0;
    #pragma unroll
    for (int j = 0; j < V41; ++j) {
        const int base = (j * NT1 + t) * 4;
        float a[4] = {va[j].x, va[j].y, va[j].z, va[j].w};
        #pragma unroll
        for (int c = 0; c < 4; ++c) {
            float x = a[c];
            if (x > bmax) { bmax = x; bmi = base + c; }   // per-thread idx increasing
            hic += (x > HI0) ? 1 : 0;
            if (x > LO0 && x <= HI0) {
                if (myn < SLOTS) sval[sbase + myn] = x;    // plain store, no atomics
                ++myn;
            }
        }
    }
    const int mynv = myn > SLOTS ? SLOTS : myn;

    // ---- One combined block reduce: argmax + #(>HI0) + window count + overflow ----
    {
        float am = bmax; int ai = bmi;
        int rh = hic, rw = myn, ro = (myn > SLOTS) ? 1 : 0;
        #pragma unroll
        for (int off = 32; off > 0; off >>= 1) {
            float ov = __shfl_down(am, off); int ai2 = __shfl_down(ai, off);
            int o1 = __shfl_down(rh, off), o2 = __shfl_down(rw, off), o3 = __shfl_down(ro, off);
            if (ov > am || (ov == am && ai2 < ai)) { am = ov; ai = ai2; }
            rh += o1; rw += o2; ro |= o3;
        }
        if (lane == 0) { redf[wid] = am; redi[wid] = ai; whi[wid] = rh; wwin[wid] = rw; wovf[wid] = ro; }
    }
    __syncthreads();   // also orders hist zeroing before histogram atomics
    float mv = redf[0]; int mi = redi[0];
    int g_hi0 = 0, win = 0, anyovf = 0;
    #pragma unroll
    for (int w = 0; w < 8; ++w) {
        if (redf[w] > mv || (redf[w] == mv && redi[w] < mi)) { mv = redf[w]; mi = redi[w]; }
        g_hi0 += whi[w]; win += wwin[w]; anyovf |= wovf[w];
    }
    const int need = (GTMAX + 1) - g_hi0;   // rank-from-top within the window
    const bool valid = (!anyovf) && (g_hi0 <= GTMAX) && (need <= win);

    float th = 0.f;
    bool done = false;   // block-uniform throughout

    if (valid) {
        // ---- Counting refinement: histogram stash, suffix-scan, exact tiny rank ----
        for (int k = 0; k < mynv; ++k)
            atomicAdd(&hist[bucket_of(sval[sbase + k])], 1);
        __syncthreads();
        const int h0 = hist[2 * t], h1 = hist[2 * t + 1];
        const int lsum = h0 + h1;
        int incl = lsum;                        // wave suffix-inclusive scan
        #pragma unroll
        for (int off = 1; off < 64; off <<= 1) {
            int v = __shfl_down(incl, off);
            incl += (lane + off < 64) ? v : 0;
        }
        if (lane == 0) wtot[wid] = incl;        // wave total
        __syncthreads();
        int suf = incl - lsum;                  // count in strictly-higher buckets (my wave)
        #pragma unroll
        for (int w = 0; w < 8; ++w) suf += (w > wid) ? wtot[w] : 0;
        int running = suf;                      // above bucket 2t+1
        if (running < need && need <= running + h1) { s_bstar = 2 * t + 1; s_above = running; }
        running += h1;                          // above bucket 2t
        if (running < need && need <= running + h0) { s_bstar = 2 * t;     s_above = running; }
        __syncthreads();
        const int bstar = s_bstar, above = s_above;
        const int cnum = hist[bstar];           // block-uniform
        if (cnum <= 64) {
            for (int k = 0; k < mynv; ++k) {
                float x = sval[sbase + k];
                if (bucket_of(x) == bstar) { int pos = atomicAdd(&s_nc, 1); cands[pos] = x; }
            }
            __syncthreads();
            const int m = s_nc;                 // == cnum, usually 1-2
            for (int i = t; i < m; i += NT1) {
                float ci = cands[i];
                int gt = 0, eq = 0;
                for (int j2 = 0; j2 < m; ++j2) {
                    float cj = cands[j2];
                    gt += (cj > ci) ? 1 : 0; eq += (cj == ci) ? 1 : 0;
                }
                int gg = g_hi0 + above + gt;
                if (gg <= GTMAX && gg + eq >= GTMAX + 1) s_th = ci;
            }
            __syncthreads();
            th = s_th;
            done = true;
        }
    }
    if (!done) {
        // ---- Exact fallback (rare, ~2%/launch): value bisection re-reading tgt (cache-warm) ----
        float lo = -1.0f, hiv = mv;
        int g_lo = HW, g_hiC = 0;
        bool degen = false;
        while (g_lo - g_hiC > 48) {
            float mid = 0.5f * (lo + hiv);
            if (!(mid > lo && mid < hiv)) { degen = true; break; }
            int cnt = 0;
            for (int j = 0; j < V41; ++j) {
                float4 v = t4[j * NT1 + t];
                cnt += (v.x > mid) + (v.y > mid) + (v.z > mid) + (v.w > mid);
            }
            #pragma unroll
            for (int off = 32; off > 0; off >>= 1) cnt += __shfl_down(cnt, off);
            if (lane == 0) wcnt[wid] = cnt;
            __syncthreads();
            int g = 0;
            #pragma unroll
            for (int w = 0; w < 8; ++w) g += wcnt[w];
            __syncthreads();
            if (g >= GTMAX + 1) { lo = mid; g_lo = g; }
            else                { hiv = mid; g_hiC = g; }
        }
        if (degen) th = hiv;
        else {
            if (t == 0) s_nc = 0;
            __syncthreads();
            for (int j = 0; j < V41; ++j) {
                float4 v = t4[j * NT1 + t];
                float a[4] = {v.x, v.y, v.z, v.w};
                for (int c2 = 0; c2 < 4; ++c2) {
                    float x = a[c2];
                    if (x > lo && x <= hiv) { int pos = atomicAdd(&s_nc, 1); if (pos < 64) cands[pos] = x; }
                }
            }
            __syncthreads();
            int m = s_nc; m = m > 64 ? 64 : m;
            for (int i = t; i < m; i += NT1) {
                float ci = cands[i];
                int gt = 0, eq = 0;
                for (int j2 = 0; j2 < m; ++j2) {
                    float cj = cands[j2];
                    gt += (cj > ci) ? 1 : 0; eq += (cj == ci) ? 1 : 0;
                }
                int gg = g_hiC + gt;
                if (gg <= GTMAX && gg + eq >= GTMAX + 1) s_th = ci;
            }
            __syncthreads();
            th = s_th;
        }
    }
    if (t == 0) { th_out[bid] = th; mi_out[bid] = mi; }
}

// ---------------- K2: pure streaming masked MSE (quarter-slice per block) ----------------
// g = exp(-d2/8) only within the 31x31 box (outside g<=1.3e-14; error ~1e-11).
__global__ __launch_bounds__(NT3, 8) void k2_mse(
    const float* __restrict__ pred, const float* __restrict__ tgt,
    const float* __restrict__ th_in, const int* __restrict__ mi_in,
    float* __restrict__ part)
{
    __shared__ float redf[4];
    const int t = threadIdx.x, lane = t & 63, wid = t >> 6;
    const int bid = blockIdx.x;
    const int s = bid >> 2, q = bid & 3;
    const float th = th_in[s];
    const int mi = mi_in[s];
    const int cyi = mi >> 7, cxi = mi & 127;
    const float4* t4 = reinterpret_cast<const float4*>(tgt)  + (size_t)s * (HW / 4) + q * 1024;
    const float4* p4 = reinterpret_cast<const float4*>(pred) + (size_t)s * (HW / 4) + q * 1024;

    float4 tv[V43], pv[V43];
    #pragma unroll
    for (int j = 0; j < V43; ++j) { tv[j] = t4[j * NT3 + t]; pv[j] = p4[j * NT3 + t]; }

    float sum = 0.f;
    #pragma unroll
    for (int j = 0; j < V43; ++j) {
        const int base = (q * 1024 + j * NT3 + t) * 4;
        float at[4] = {tv[j].x, tv[j].y, tv[j].z, tv[j].w};
        float ap[4] = {pv[j].x, pv[j].y, pv[j].z, pv[j].w};
        #pragma unroll
        for (int c = 0; c < 4; ++c) {
            if (at[c] > th) {
                const int idx = base + c;
                const int dy = (idx >> 7) - cyi, dx = (idx & 127) - cxi;
                float p = ap[c];
                if (dy >= -15 && dy <= 15 && dx >= -15 && dx <= 15) {
                    float g = __expf((float)(dy * dy + dx * dx) * -0.125f);
                    float d = p - g;
                    sum += d * d;
                } else {
                    sum += p * p;
                }
            }
        }
    }
    #pragma unroll
    for (int off = 32; off > 0; off >>= 1) sum += __shfl_down(sum, off);
    if (lane == 0) redf[wid] = sum;
    __syncthreads();
    if (t == 0) part[bid] = (redf[0] + redf[1]) + (redf[2] + redf[3]);
}

// ---------------- K3: final reduce ----------------
__global__ __launch_bounds__(256) void k3_final(
    const float* __restrict__ part, float* __restrict__ out)
{
    __shared__ float red[4];
    const int t = threadIdx.x;
    float s = 0.f;
    for (int i = t; i < NPART; i += 256) s += part[i];
    #pragma unroll
    for (int off = 32; off > 0; off >>= 1) s += __shfl_down(s, off);
    if ((t & 63) == 0) red[t >> 6] = s;
    __syncthreads();
    if (t == 0)
        out[0] = ((red[0] + red[1]) + (red[2] + red[3]))
                 * (1.0f / ((float)GTMAX * (float)NSLICE));   // / pxl_num / (B*K)
}

extern "C" void kernel_launch(void* const* d_in, const int* in_sizes, int n_in,
                              void* d_out, int out_size, void* d_ws, size_t ws_size,
                              hipStream_t stream)
{
    const float* pred = (const float*)d_in[0];   // "output" in reference
    const float* tgt  = (const float*)d_in[1];   // "target"
    float* out = (float*)d_out;

    // workspace layout (floats): [0,1088) th | [1088,2176) mi (int) | [2176,6528) partials
    float* th   = (float*)d_ws;
    int*   mi   = (int*)(th + NSLICE);
    float* part = (float*)(mi + NSLICE);

    k1_scan_select<<<NSLICE,       NT1, 0, stream>>>(tgt, th, mi);
    k2_mse        <<<NSLICE * QPS, NT3, 0, stream>>>(pred, tgt, th, mi, part);
    k3_final      <<<1,            256, 0, stream>>>(part, out);
}